// Round 1
// baseline (108.003 us; speedup 1.0000x reference)
//
#include <hip/hip_runtime.h>

typedef __attribute__((ext_vector_type(4))) float f32x4;
typedef __attribute__((ext_vector_type(8))) short bf16x8;

#define IDIM   128
#define HID    64
#define TDEPTH 6
#define MTILE  64
#define NWAVES 6
#define BLOCK  (NWAVES * 64)
#define WFRAG_ELEMS (6 * 4 * 4 * 512)   // nd, ks, ct, lane*8+j

__device__ __forceinline__ unsigned short f2bf(float f) {
    unsigned int u = __builtin_bit_cast(unsigned int, f);
    unsigned int r = (u + 0x7FFFu + ((u >> 16) & 1u)) >> 16;  // RNE
    return (unsigned short)r;
}

// Pre-convert W1 (only the 6 chain nodes) into bf16 MFMA B-fragment layout.
// B-frag for mfma_f32_16x16x32_bf16: lane holds B[k = (lane>>4)*8 + j][n = lane&15]
__global__ void prep_wfrag(const float* __restrict__ W1, unsigned short* __restrict__ wfrag) {
    int idx = blockIdx.x * 256 + threadIdx.x;
    if (idx >= WFRAG_ELEMS) return;
    int j    = idx & 7;
    int lane = (idx >> 3) & 63;
    int ct   = (idx >> 9) & 3;
    int ks   = (idx >> 11) & 3;
    int nd   = idx >> 13;
    int node = (1 << nd) - 1;              // chain node: 0,1,3,7,15,31
    int k    = ks * 32 + (lane >> 4) * 8 + j;
    int col  = ct * 16 + (lane & 15);
    wfrag[idx] = f2bf(W1[(node * IDIM + k) * HID + col]);
}

template <bool USE_WS>
__global__ __launch_bounds__(BLOCK, 3)
void sdt_kernel(const float* __restrict__ x, const float* __restrict__ W1,
                const float* __restrict__ b1, const float* __restrict__ W2,
                const float* __restrict__ b2, const float* __restrict__ leaf,
                const unsigned short* __restrict__ wfrag, float* __restrict__ out) {
    __shared__ unsigned short xs[MTILE][IDIM + 8];   // +8 pad: 2-way bank alias (free)
    __shared__ float p_lds[TDEPTH][MTILE];

    const int tid    = threadIdx.x;
    const int m_base = blockIdx.x * MTILE;

    // ---- stage X tile: fp32 global -> bf16 LDS (coalesced float4 loads) ----
    const float4* xv = reinterpret_cast<const float4*>(x) + (size_t)m_base * (IDIM / 4);
    for (int f = tid; f < MTILE * (IDIM / 4); f += BLOCK) {
        int row = f >> 5;                 // 32 float4 per row
        int c4  = f & 31;
        float4 v = xv[row * 32 + c4];
        unsigned long long pk =
            (unsigned long long)f2bf(v.x) |
            ((unsigned long long)f2bf(v.y) << 16) |
            ((unsigned long long)f2bf(v.z) << 32) |
            ((unsigned long long)f2bf(v.w) << 48);
        *reinterpret_cast<unsigned long long*>(&xs[row][c4 * 4]) = pk;
    }
    __syncthreads();

    const int wave = tid >> 6;            // 0..5 == depth index k
    const int lane = tid & 63;
    const int node = (1 << wave) - 1;
    const int lcol = lane & 15;
    const int lq   = lane >> 4;

    f32x4 acc[4][4];
    #pragma unroll
    for (int rt = 0; rt < 4; rt++)
        #pragma unroll
        for (int ct = 0; ct < 4; ct++)
            acc[rt][ct] = (f32x4){0.f, 0.f, 0.f, 0.f};

    // ---- GEMM: 64 rows x 64 cols per wave, K=128 in 4 steps ----
    #pragma unroll
    for (int ks = 0; ks < 4; ks++) {
        bf16x8 bfrag[4];
        if (USE_WS) {
            #pragma unroll
            for (int ct = 0; ct < 4; ct++)
                bfrag[ct] = *reinterpret_cast<const bf16x8*>(
                    wfrag + (((wave * 4 + ks) * 4 + ct) * 512 + lane * 8));
        } else {
            const float* wsrc = W1 + (size_t)node * IDIM * HID;
            int k0 = ks * 32 + lq * 8;
            #pragma unroll
            for (int ct = 0; ct < 4; ct++) {
                int col = ct * 16 + lcol;
                bf16x8 v;
                #pragma unroll
                for (int j = 0; j < 8; j++)
                    v[j] = (short)f2bf(wsrc[(k0 + j) * HID + col]);
                bfrag[ct] = v;
            }
        }
        bf16x8 afrag[4];
        #pragma unroll
        for (int rt = 0; rt < 4; rt++)
            afrag[rt] = *reinterpret_cast<const bf16x8*>(&xs[rt * 16 + lcol][ks * 32 + lq * 8]);
        #pragma unroll
        for (int rt = 0; rt < 4; rt++)
            #pragma unroll
            for (int ct = 0; ct < 4; ct++)
                acc[rt][ct] = __builtin_amdgcn_mfma_f32_16x16x32_bf16(
                    afrag[rt], bfrag[ct], acc[rt][ct], 0, 0, 0);
    }

    // ---- epilogue: relu, dot W2, sigmoid ----
    // C layout: col = ct*16 + lcol, row = rt*16 + lq*4 + r
    float b1v[4], w2v[4];
    #pragma unroll
    for (int ct = 0; ct < 4; ct++) {
        int col = ct * 16 + lcol;
        b1v[ct] = b1[node * HID + col];
        w2v[ct] = W2[node * HID + col];
    }
    const float bias2 = b2[node];
    #pragma unroll
    for (int rt = 0; rt < 4; rt++) {
        #pragma unroll
        for (int r = 0; r < 4; r++) {
            float s = 0.f;
            #pragma unroll
            for (int ct = 0; ct < 4; ct++) {
                float v = acc[rt][ct][r] + b1v[ct];
                v = v > 0.f ? v : 0.f;
                s += v * w2v[ct];
            }
            #pragma unroll
            for (int d = 1; d < 16; d <<= 1)
                s += __shfl_xor(s, d, 64);
            float p = 1.f / (1.f + __expf(-(s + bias2)));
            if (lcol == 0)
                p_lds[wave][rt * 16 + lq * 4 + r] = p;
        }
    }
    __syncthreads();

    // ---- fold: out[b] = sum_l leaf[l] * prod_k (bit_k(l) ? p_k : 1-p_k) ----
    if (tid < MTILE) {
        float pk[TDEPTH];
        #pragma unroll
        for (int k = 0; k < TDEPTH; k++) pk[k] = p_lds[k][tid];
        float o = 0.f;
        for (int l = 0; l < 64; l++) {
            float w = leaf[l];
            #pragma unroll
            for (int k = 0; k < TDEPTH; k++)
                w *= ((l >> k) & 1) ? pk[k] : (1.f - pk[k]);
            o += w;
        }
        out[m_base + tid] = o;
    }
}

extern "C" void kernel_launch(void* const* d_in, const int* in_sizes, int n_in,
                              void* d_out, int out_size, void* d_ws, size_t ws_size,
                              hipStream_t stream) {
    const float* x    = (const float*)d_in[0];
    const float* W1   = (const float*)d_in[1];
    const float* b1   = (const float*)d_in[2];
    const float* W2   = (const float*)d_in[3];
    const float* b2   = (const float*)d_in[4];
    const float* leaf = (const float*)d_in[5];
    float* out = (float*)d_out;

    const int Bn = in_sizes[0] / IDIM;     // 65536
    const int nblocks = Bn / MTILE;        // 1024

    if (ws_size >= (size_t)WFRAG_ELEMS * sizeof(unsigned short)) {
        unsigned short* wfrag = (unsigned short*)d_ws;
        prep_wfrag<<<(WFRAG_ELEMS + 255) / 256, 256, 0, stream>>>(W1, wfrag);
        sdt_kernel<true><<<nblocks, BLOCK, 0, stream>>>(x, W1, b1, W2, b2, leaf, wfrag, out);
    } else {
        sdt_kernel<false><<<nblocks, BLOCK, 0, stream>>>(x, W1, b1, W2, b2, leaf, nullptr, out);
    }
}

// Round 2
// 107.722 us; speedup vs baseline: 1.0026x; 1.0026x over previous
//
#include <hip/hip_runtime.h>

typedef __attribute__((ext_vector_type(4))) float f32x4;
typedef __attribute__((ext_vector_type(8))) short bf16x8;

#define IDIM   128
#define HID    64
#define TDEPTH 6
#define MTILE  64
#define NWAVES 6
#define BLOCK  (NWAVES * 64)
#define WFRAG_ELEMS (6 * 4 * 4 * 512)   // nd, ks, ct, lane*8+j

__device__ __forceinline__ unsigned short f2bf(float f) {
    unsigned int u = __builtin_bit_cast(unsigned int, f);
    unsigned int r = (u + 0x7FFFu + ((u >> 16) & 1u)) >> 16;  // RNE
    return (unsigned short)r;
}

// Pre-convert W1 (only the 6 chain nodes) into bf16 MFMA B-fragment layout.
// B-frag for mfma_f32_16x16x32_bf16: lane holds B[k = (lane>>4)*8 + j][n = lane&15]
__global__ void prep_wfrag(const float* __restrict__ W1, unsigned short* __restrict__ wfrag) {
    int idx = blockIdx.x * 256 + threadIdx.x;
    if (idx >= WFRAG_ELEMS) return;
    int j    = idx & 7;
    int lane = (idx >> 3) & 63;
    int ct   = (idx >> 9) & 3;
    int ks   = (idx >> 11) & 3;
    int nd   = idx >> 13;
    int node = (1 << nd) - 1;              // chain node: 0,1,3,7,15,31
    int k    = ks * 32 + (lane >> 4) * 8 + j;
    int col  = ct * 16 + (lane & 15);
    wfrag[idx] = f2bf(W1[(node * IDIM + k) * HID + col]);
}

template <bool USE_WS>
__global__ __launch_bounds__(BLOCK, 3)
void sdt_kernel(const float* __restrict__ x, const float* __restrict__ W1,
                const float* __restrict__ b1, const float* __restrict__ W2,
                const float* __restrict__ b2, const float* __restrict__ leaf,
                const unsigned short* __restrict__ wfrag, float* __restrict__ out) {
    __shared__ unsigned short xs[MTILE][IDIM + 8];   // +8 pad: 2-way bank alias (free)
    __shared__ float p_lds[TDEPTH][MTILE];
    __shared__ float pp[4][MTILE];

    const int tid    = threadIdx.x;
    const int m_base = blockIdx.x * MTILE;

    // ---- stage X tile: fp32 global -> bf16 LDS (coalesced float4 loads) ----
    const float4* xv = reinterpret_cast<const float4*>(x) + (size_t)m_base * (IDIM / 4);
    for (int f = tid; f < MTILE * (IDIM / 4); f += BLOCK) {
        int row = f >> 5;                 // 32 float4 per row
        int c4  = f & 31;
        float4 v = xv[row * 32 + c4];
        unsigned long long pk =
            (unsigned long long)f2bf(v.x) |
            ((unsigned long long)f2bf(v.y) << 16) |
            ((unsigned long long)f2bf(v.z) << 32) |
            ((unsigned long long)f2bf(v.w) << 48);
        *reinterpret_cast<unsigned long long*>(&xs[row][c4 * 4]) = pk;
    }

    const int wave = tid >> 6;            // 0..5 == depth index k
    const int lane = tid & 63;
    const int node = (1 << wave) - 1;
    const int lcol = lane & 15;
    const int lq   = lane >> 4;

    // hoist epilogue params so their latency hides under the GEMM
    float b1v[4], w2v[4];
    #pragma unroll
    for (int ct = 0; ct < 4; ct++) {
        int col = ct * 16 + lcol;
        b1v[ct] = b1[node * HID + col];
        w2v[ct] = W2[node * HID + col];
    }
    const float bias2 = b2[node];

    __syncthreads();

    f32x4 acc[4][4];
    #pragma unroll
    for (int rt = 0; rt < 4; rt++)
        #pragma unroll
        for (int ct = 0; ct < 4; ct++)
            acc[rt][ct] = (f32x4){0.f, 0.f, 0.f, 0.f};

    // ---- GEMM: 64 rows x 64 cols per wave, K=128 in 4 steps ----
    #pragma unroll
    for (int ks = 0; ks < 4; ks++) {
        bf16x8 bfrag[4];
        if (USE_WS) {
            #pragma unroll
            for (int ct = 0; ct < 4; ct++)
                bfrag[ct] = *reinterpret_cast<const bf16x8*>(
                    wfrag + (((wave * 4 + ks) * 4 + ct) * 512 + lane * 8));
        } else {
            const float* wsrc = W1 + (size_t)node * IDIM * HID;
            int k0 = ks * 32 + lq * 8;
            #pragma unroll
            for (int ct = 0; ct < 4; ct++) {
                int col = ct * 16 + lcol;
                bf16x8 v;
                #pragma unroll
                for (int j = 0; j < 8; j++)
                    v[j] = (short)f2bf(wsrc[(k0 + j) * HID + col]);
                bfrag[ct] = v;
            }
        }
        bf16x8 afrag[4];
        #pragma unroll
        for (int rt = 0; rt < 4; rt++)
            afrag[rt] = *reinterpret_cast<const bf16x8*>(&xs[rt * 16 + lcol][ks * 32 + lq * 8]);
        #pragma unroll
        for (int rt = 0; rt < 4; rt++)
            #pragma unroll
            for (int ct = 0; ct < 4; ct++)
                acc[rt][ct] = __builtin_amdgcn_mfma_f32_16x16x32_bf16(
                    afrag[rt], bfrag[ct], acc[rt][ct], 0, 0, 0);
    }

    // ---- epilogue: relu, dot W2, sigmoid ----
    // C layout: col = ct*16 + lcol, row = rt*16 + lq*4 + r
    #pragma unroll
    for (int rt = 0; rt < 4; rt++) {
        #pragma unroll
        for (int r = 0; r < 4; r++) {
            float s = 0.f;
            #pragma unroll
            for (int ct = 0; ct < 4; ct++) {
                float v = acc[rt][ct][r] + b1v[ct];
                v = v > 0.f ? v : 0.f;
                s += v * w2v[ct];
            }
            #pragma unroll
            for (int d = 1; d < 16; d <<= 1)
                s += __shfl_xor(s, d, 64);
            float p = 1.f / (1.f + __expf(-(s + bias2)));
            if (lcol == 0)
                p_lds[wave][rt * 16 + lq * 4 + r] = p;
        }
    }
    __syncthreads();

    // ---- fold: out[b] = sum_l leaf[l] * prod_k (bit_k(l) ? p_k : 1-p_k) ----
    // Distributed across 4 waves: chunk = bits 4..5 of leaf index (hoisted
    // factor), inner 16 leaves contracted by a 4-level DP (15 lerps).
    if (tid < 4 * MTILE) {
        int row = tid & (MTILE - 1);
        int ch  = tid >> 6;               // 0..3
        float q0 = p_lds[0][row];
        float q1 = p_lds[1][row];
        float q2 = p_lds[2][row];
        float q3 = p_lds[3][row];
        float p4 = p_lds[4][row];
        float p5 = p_lds[5][row];
        float f4 = (ch & 1) ? p4 : 1.f - p4;
        float f5 = (ch & 2) ? p5 : 1.f - p5;
        const float* lf = leaf + ch * 16;
        float t[8];
        #pragma unroll
        for (int j = 0; j < 8; j++) {
            float a = lf[2 * j], b = lf[2 * j + 1];
            t[j] = a + q0 * (b - a);      // contract bit 0
        }
        #pragma unroll
        for (int j = 0; j < 4; j++) t[j] = t[2 * j] + q1 * (t[2 * j + 1] - t[2 * j]);
        #pragma unroll
        for (int j = 0; j < 2; j++) t[j] = t[2 * j] + q2 * (t[2 * j + 1] - t[2 * j]);
        float s = t[0] + q3 * (t[1] - t[0]);
        pp[ch][row] = f4 * f5 * s;
    }
    __syncthreads();
    if (tid < MTILE)
        out[m_base + tid] = (pp[0][tid] + pp[1][tid]) + (pp[2][tid] + pp[3][tid]);
}

extern "C" void kernel_launch(void* const* d_in, const int* in_sizes, int n_in,
                              void* d_out, int out_size, void* d_ws, size_t ws_size,
                              hipStream_t stream) {
    const float* x    = (const float*)d_in[0];
    const float* W1   = (const float*)d_in[1];
    const float* b1   = (const float*)d_in[2];
    const float* W2   = (const float*)d_in[3];
    const float* b2   = (const float*)d_in[4];
    const float* leaf = (const float*)d_in[5];
    float* out = (float*)d_out;

    const int Bn = in_sizes[0] / IDIM;     // 65536
    const int nblocks = Bn / MTILE;        // 1024

    if (ws_size >= (size_t)WFRAG_ELEMS * sizeof(unsigned short)) {
        unsigned short* wfrag = (unsigned short*)d_ws;
        prep_wfrag<<<(WFRAG_ELEMS + 255) / 256, 256, 0, stream>>>(W1, wfrag);
        sdt_kernel<true><<<nblocks, BLOCK, 0, stream>>>(x, W1, b1, W2, b2, leaf, wfrag, out);
    } else {
        sdt_kernel<false><<<nblocks, BLOCK, 0, stream>>>(x, W1, b1, W2, b2, leaf, nullptr, out);
    }
}